// Round 7
// baseline (642.370 us; speedup 1.0000x reference)
//
#include <hip/hip_runtime.h>
#include <cmath>

#define T_SAMPLE 300
#define NCHUNK 75   // T / 4

struct RefK { float v[10]; };

// One step of the SLAYER spike recurrence. buf[0..9] = pending refractory.
__device__ __forceinline__ unsigned char spike_step(float u, float* buf, const RefK& rk) {
    const float um = u + buf[0];
    const bool fire = um >= 10.0f;
    const float ev = fire ? 1.0f : 0.0f;
#pragma unroll
    for (int r = 0; r < 9; ++r) buf[r] = fmaf(ev, rk.v[r], buf[r + 1]);
    buf[9] = ev * rk.v[9];
    return fire ? (unsigned char)1 : (unsigned char)0;
}

// ---------------------------------------------------------------------------
// transpose input [B,2,34,34,T] f32 ({0,1}) -> X[tchunk][n][4] u8, n = b,c,y,x
// ---------------------------------------------------------------------------
__global__ __launch_bounds__(256) void transpose_in_kernel(
    const float* __restrict__ In, unsigned int* __restrict__ X)
{
    __shared__ unsigned int lds[16 * NCHUNK];
    const int blk = blockIdx.x;          // 1156 blocks x 16 neurons
    const int tn = threadIdx.x >> 4;     // 0..15 neuron
    const int tq = threadIdx.x & 15;     // 0..15 t-group
    const size_t n = (size_t)blk * 16 + tn;
#pragma unroll
    for (int p = 0; p < 5; ++p) {
        const int ch = p * 16 + tq;
        if (ch < NCHUNK) {
            const float4 v = *(const float4*)(In + n * T_SAMPLE + ch * 4);
            unsigned int u = (v.x != 0.f ? 1u : 0u) | (v.y != 0.f ? 0x100u : 0u) |
                             (v.z != 0.f ? 0x10000u : 0u) | (v.w != 0.f ? 0x1000000u : 0u);
            lds[tn * NCHUNK + ch] = u;
        }
    }
    __syncthreads();
    for (int idx = threadIdx.x; idx < 16 * NCHUNK; idx += 256) {
        const int ch = idx >> 4, t2 = idx & 15;
        X[(size_t)ch * 18496 + blk * 16 + t2] = lds[t2 * NCHUNK + ch];
    }
}

// ---------------------------------------------------------------------------
// conv_u: 2D conv (pad=1) for ONE timestep per block. Tile row (all tiles at
// ty) staged once as f32 in LDS; b32 reads are conflict-free (<=2-way) at
// strides 10/18/36. Each wave computes OPT=16 output channels (weights ->
// SGPRs, acc = 16 VGPRs) => 16 FMAs per LDS read, VALU-bound.
// Grid: x = t (300), y = ty, z = local batch. Block 256 = 4 waves:
// wave -> (tile txw = wave/CHG, channel group chg = wave%CHG), CHG = OC/16.
// Output U: f32 [t][NBL*OC*OH*OW] (=32768 plane), coalesced dword stores.
// ---------------------------------------------------------------------------
template <int IC, int OC, int K, int OH, int OW, int IH, int IW, int NBL>
__global__ __launch_bounds__(256) void conv_u_kernel(
    const unsigned int* __restrict__ in_, const float* __restrict__ W,
    float* __restrict__ U, int b0)
{
    constexpr int TH = 8, TW = 8;
    constexpr int EH = TH + K - 1;       // extended rows
    constexpr int EWC = OW + K - 1;      // combined extended width (full row)
    constexpr int KK = K * K;
    constexpr int OPT = 16;
    constexpr int CHG = OC / OPT;        // channel groups per tile
    constexpr int ES = IC * EH * EWC;
    constexpr int PLANE_IN = 8 * IC * IH * IW;   // full-batch chunk plane (u32)
    constexpr int PLANE_U = NBL * OC * OH * OW;  // = 32768 for all three convs

    __shared__ float tile[ES];

    const int t = blockIdx.x;            // 0..299
    const int tc = t >> 2, tb = t & 3;   // source chunk, byte lane
    const int ty = blockIdx.y;
    const int bl = blockIdx.z;
    const int b = b0 + bl;
    const int tid = threadIdx.x;
    const int wave = tid >> 6, lane = tid & 63;
    const int py = lane >> 3, px = lane & 7;
    const int txw = wave / CHG;
    const int chg = wave % CHG;

    // ---- stage one t-plane of the tile row (coalesced u32, extract byte) ----
    const unsigned int* ib = in_ + (size_t)tc * PLANE_IN + (size_t)b * IC * IH * IW;
    const int gy0 = ty * TH - 1;         // PAD = 1
    for (int e = tid; e < ES; e += 256) {
        const int c = e / (EH * EWC);
        const int r = e % (EH * EWC);
        const int iy = r / EWC, ix = r % EWC;
        const int gy = gy0 + iy, gx = ix - 1;
        float v = 0.f;
        if ((unsigned)gy < (unsigned)IH && (unsigned)gx < (unsigned)IW)
            v = (float)((ib[(c * IH + gy) * IW + gx] >> (8 * tb)) & 0xffu);
        tile[e] = v;
    }
    __syncthreads();

    // ---- compute ----
    float acc[OPT];
#pragma unroll
    for (int j = 0; j < OPT; ++j) acc[j] = 0.f;

    int ob = chg * OPT;
    ob = __builtin_amdgcn_readfirstlane(ob);   // wave-uniform -> scalar weight loads
    const float* Wp = W + (size_t)ob * IC * KK;
    const int xoff = txw * TW + px;

    for (int c = 0; c < IC; ++c) {
#pragma unroll
        for (int dy = 0; dy < K; ++dy) {
            float wr[OPT][K];
#pragma unroll
            for (int j = 0; j < OPT; ++j)
#pragma unroll
                for (int dx = 0; dx < K; ++dx)
                    wr[j][dx] = Wp[(j * IC + c) * KK + dy * K + dx];
            const float* trow = &tile[(c * EH + py + dy) * EWC + xoff];
#pragma unroll
            for (int dx = 0; dx < K; ++dx) {
                const float v = trow[dx];
#pragma unroll
                for (int j = 0; j < OPT; ++j)
                    acc[j] = fmaf(wr[j][dx], v, acc[j]);
            }
        }
    }

    // ---- coalesced dword stores ----
    const int y = ty * TH + py;
#pragma unroll
    for (int j = 0; j < OPT; ++j) {
        const int nb = ((bl * OC + (ob + j)) * OH + y) * OW + xoff;
        U[(size_t)t * PLANE_U + nb] = acc[j];
    }
}

// ---------------------------------------------------------------------------
// spike: per-neuron scan. U f32 [t][nneur] in, uchar4 per chunk out.
// 64-thread blocks (512 blocks -> all CUs active). Ring-8 = 32 loads in flight.
// ---------------------------------------------------------------------------
__global__ __launch_bounds__(64) void spike_kernel(
    const float* __restrict__ U, uchar4* __restrict__ S,
    int nneur, int sstride, int soff, RefK rk)
{
    const int n = blockIdx.x * 64 + threadIdx.x;
    const float* up = U + n;
    uchar4* sp = S + soff + n;
    float buf[10];
#pragma unroll
    for (int r = 0; r < 10; ++r) buf[r] = 0.f;

    float ring[8][4];
#pragma unroll
    for (int r = 0; r < 8; ++r)
#pragma unroll
        for (int k = 0; k < 4; ++k) ring[r][k] = up[(size_t)(4 * r + k) * nneur];

#pragma unroll 8
    for (int ch = 0; ch < 72; ++ch) {
        float cur[4];
#pragma unroll
        for (int k = 0; k < 4; ++k) cur[k] = ring[ch & 7][k];
        const int pf = (ch + 8 < NCHUNK) ? ch + 8 : NCHUNK - 1;
#pragma unroll
        for (int k = 0; k < 4; ++k) ring[ch & 7][k] = up[(size_t)(4 * pf + k) * nneur];
        uchar4 o;
        o.x = spike_step(cur[0], buf, rk);
        o.y = spike_step(cur[1], buf, rk);
        o.z = spike_step(cur[2], buf, rk);
        o.w = spike_step(cur[3], buf, rk);
        sp[(size_t)ch * sstride] = o;
    }
#pragma unroll
    for (int ch = 72; ch < NCHUNK; ++ch) {
        uchar4 o;
        o.x = spike_step(ring[ch & 7][0], buf, rk);
        o.y = spike_step(ring[ch & 7][1], buf, rk);
        o.z = spike_step(ring[ch & 7][2], buf, rk);
        o.w = spike_step(ring[ch & 7][3], buf, rk);
        sp[(size_t)ch * sstride] = o;
    }
}

// ---------------------------------------------------------------------------
// pool(2)*11 + spike. Two 8-byte loads per chunk (x-pair rows). Ring-8.
// 64-thread blocks.
// ---------------------------------------------------------------------------
__device__ __forceinline__ int bsum4(uint2 r0, uint2 r1, int k) {
    return (int)((r0.x >> (8 * k)) & 0xffu) + (int)((r0.y >> (8 * k)) & 0xffu)
         + (int)((r1.x >> (8 * k)) & 0xffu) + (int)((r1.y >> (8 * k)) & 0xffu);
}

template <int C, int H, int W>
__global__ __launch_bounds__(64) void pool_spike_kernel(
    const uchar4* __restrict__ Sin, uchar4* __restrict__ Sout, RefK rk)
{
    constexpr int H2 = H / 2, W2 = W / 2;
    constexpr int SIN = 8 * C * H * W;     // chunk stride (uchar4 units)
    constexpr int SOUT = 8 * C * H2 * W2;
    const int n = blockIdx.x * 64 + threadIdx.x;   // exact multiple of 64
    const int x = n % W2;
    const int y = (n / W2) % H2;
    const int c = (n / (W2 * H2)) % C;
    const int b = n / (W2 * H2 * C);
    const int base = (((b * C + c) * H + 2 * y) * W + 2 * x);
    uchar4* q = Sout + n;

    float buf[10];
#pragma unroll
    for (int r = 0; r < 10; ++r) buf[r] = 0.f;

    uint2 r0[8], r1[8];
#pragma unroll
    for (int r = 0; r < 8; ++r) {
        r0[r] = *(const uint2*)(Sin + (size_t)r * SIN + base);
        r1[r] = *(const uint2*)(Sin + (size_t)r * SIN + base + W);
    }

#pragma unroll 8
    for (int ch = 0; ch < 72; ++ch) {
        const uint2 a0 = r0[ch & 7], a1 = r1[ch & 7];
        const int pf = (ch + 8 < NCHUNK) ? ch + 8 : NCHUNK - 1;
        r0[ch & 7] = *(const uint2*)(Sin + (size_t)pf * SIN + base);
        r1[ch & 7] = *(const uint2*)(Sin + (size_t)pf * SIN + base + W);
        uchar4 o;
        o.x = spike_step(11.0f * (float)bsum4(a0, a1, 0), buf, rk);
        o.y = spike_step(11.0f * (float)bsum4(a0, a1, 1), buf, rk);
        o.z = spike_step(11.0f * (float)bsum4(a0, a1, 2), buf, rk);
        o.w = spike_step(11.0f * (float)bsum4(a0, a1, 3), buf, rk);
        q[(size_t)ch * SOUT] = o;
    }
#pragma unroll
    for (int ch = 72; ch < NCHUNK; ++ch) {
        const uint2 a0 = r0[ch & 7], a1 = r1[ch & 7];
        uchar4 o;
        o.x = spike_step(11.0f * (float)bsum4(a0, a1, 0), buf, rk);
        o.y = spike_step(11.0f * (float)bsum4(a0, a1, 1), buf, rk);
        o.z = spike_step(11.0f * (float)bsum4(a0, a1, 2), buf, rk);
        o.w = spike_step(11.0f * (float)bsum4(a0, a1, 3), buf, rk);
        q[(size_t)ch * SOUT] = o;
    }
}

// ---------------------------------------------------------------------------
// dense u: U6[tc][b*10+o][4] = sum_site wfc[o,site] * s5[tc][b*4096+site][4]
// ---------------------------------------------------------------------------
__global__ __launch_bounds__(64) void dense_u_kernel(
    const uchar4* __restrict__ S5, const float* __restrict__ WFC,
    float4* __restrict__ U6)
{
    const int tc = blockIdx.x, o = blockIdx.y, b = blockIdx.z;
    const int lane = threadIdx.x;
    float a0 = 0.f, a1 = 0.f, a2 = 0.f, a3 = 0.f;
    const uchar4* sb = S5 + (size_t)tc * 32768 + b * 4096;
    const float* wb = WFC + o * 4096;
    for (int i = 0; i < 64; ++i) {
        const int site = i * 64 + lane;
        const uchar4 s = sb[site];
        const float w = wb[site];
        a0 = fmaf(w, (float)s.x, a0);
        a1 = fmaf(w, (float)s.y, a1);
        a2 = fmaf(w, (float)s.z, a2);
        a3 = fmaf(w, (float)s.w, a3);
    }
#pragma unroll
    for (int m = 1; m < 64; m <<= 1) {
        a0 += __shfl_xor(a0, m, 64);
        a1 += __shfl_xor(a1, m, 64);
        a2 += __shfl_xor(a2, m, 64);
        a3 += __shfl_xor(a3, m, 64);
    }
    if (lane == 0)
        U6[(size_t)tc * 80 + b * 10 + o] = make_float4(a0, a1, a2, a3);
}

// final spike over 80 neurons; float4 chunks in, [n][t] fp32 out.
__global__ __launch_bounds__(128) void spike6_kernel(
    const float4* __restrict__ U6, float* __restrict__ Out, RefK rk)
{
    const int n = threadIdx.x;
    if (n >= 80) return;
    const float4* up = U6 + n;
    float* op = Out + (size_t)n * T_SAMPLE;
    float buf[10];
#pragma unroll
    for (int r = 0; r < 10; ++r) buf[r] = 0.f;

    float4 ring[8];
#pragma unroll
    for (int r = 0; r < 8; ++r) ring[r] = up[(size_t)r * 80];

#pragma unroll 8
    for (int ch = 0; ch < 72; ++ch) {
        const float4 cur = ring[ch & 7];
        const int pf = (ch + 8 < NCHUNK) ? ch + 8 : NCHUNK - 1;
        ring[ch & 7] = up[(size_t)pf * 80];
        float4 o;
        o.x = (float)spike_step(cur.x, buf, rk);
        o.y = (float)spike_step(cur.y, buf, rk);
        o.z = (float)spike_step(cur.z, buf, rk);
        o.w = (float)spike_step(cur.w, buf, rk);
        *(float4*)(op + ch * 4) = o;
    }
#pragma unroll
    for (int ch = 72; ch < NCHUNK; ++ch) {
        const float4 cur = ring[ch & 7];
        float4 o;
        o.x = (float)spike_step(cur.x, buf, rk);
        o.y = (float)spike_step(cur.y, buf, rk);
        o.z = (float)spike_step(cur.z, buf, rk);
        o.w = (float)spike_step(cur.w, buf, rk);
        *(float4*)(op + ch * 4) = o;
    }
}

extern "C" void kernel_launch(void* const* d_in, const int* in_sizes, int n_in,
                              void* d_out, int out_size, void* d_ws, size_t ws_size,
                              hipStream_t stream)
{
    const float* spikeIn = (const float*)d_in[0];  // [8,2,34,34,300]
    const float* w1 = (const float*)d_in[1];       // [16,2,5,5]
    const float* w2 = (const float*)d_in[2];       // [32,16,3,3]
    const float* w3 = (const float*)d_in[3];       // [64,32,3,3]
    const float* wfc = (const float*)d_in[4];      // [10,64,8,8]
    float* out = (float*)d_out;                    // [8,10,1,1,300]

    RefK rk;
    for (int t = 1; t <= 10; ++t)
        rk.v[t - 1] = (float)(-20.0 * (double)t * std::exp(1.0 - (double)t));

    // workspace (~88.6 MB):
    //   U : 39.3216 MB  f32 [300][32768] u planes (all three convs)
    //   A : 39.3216 MB  uchar4 [75][neuron] s1 -> s3 -> s5
    //   B :  9.8304 MB  uchar4 X (5.55 MB) then s2 -> s4
    //   U6:  0.096  MB  float4[75*80]
    char* ws = (char*)d_ws;
    const size_t U_BYTES = 39321600;
    const size_t A_BYTES = 39321600;
    const size_t B_BYTES = 9830400;
    float* U = (float*)ws;
    uchar4* A = (uchar4*)(ws + U_BYTES);
    uchar4* Bb = (uchar4*)(ws + U_BYTES + A_BYTES);
    float4* U6 = (float4*)(ws + U_BYTES + A_BYTES + B_BYTES);

    uchar4* X = Bb;   // input transpose; dead after layer 1
    uchar4* s1 = A;
    uchar4* s2 = Bb;
    uchar4* s3 = A;   // s1 dead after pool2
    uchar4* s4 = Bb;  // s2 dead after conv2-u
    uchar4* s5 = A;   // s3 dead after pool4

    // ---- input transpose ----
    transpose_in_kernel<<<18496 / 16, 256, 0, stream>>>(spikeIn, (unsigned int*)X);

    // ---- layer 1: conv(2->16, k5) + spike, batch pairs ----
    for (int b0 = 0; b0 < 8; b0 += 2) {
        dim3 g1(300, 4, 2);   // ty rows, 4 tiles/row (1 wave each), 16 ch/wave
        conv_u_kernel<2, 16, 5, 32, 32, 34, 34, 2>
            <<<g1, 256, 0, stream>>>((const unsigned int*)X, w1, U, b0);
        spike_kernel<<<32768 / 64, 64, 0, stream>>>(
            U, s1, 32768, 131072, b0 * 16384, rk);
    }
    // ---- pool2 + spike ----
    pool_spike_kernel<16, 32, 32><<<32768 / 64, 64, 0, stream>>>(s1, s2, rk);
    // ---- layer 2: conv(16->32, k3) + spike, batch halves ----
    for (int b0 = 0; b0 < 8; b0 += 4) {
        dim3 g2(300, 2, 4);   // 2 tile rows, 2 tiles x 2 ch-groups
        conv_u_kernel<16, 32, 3, 16, 16, 16, 16, 4>
            <<<g2, 256, 0, stream>>>((const unsigned int*)s2, w2, U, b0);
        spike_kernel<<<32768 / 64, 64, 0, stream>>>(
            U, s3, 32768, 65536, b0 * 8192, rk);
    }
    // ---- pool4 + spike ----
    pool_spike_kernel<32, 16, 16><<<16384 / 64, 64, 0, stream>>>(s3, s4, rk);
    // ---- layer 3: conv(32->64, k3) + spike, full batch ----
    {
        dim3 g3(300, 1, 8);   // 1 tile, 4 ch-groups
        conv_u_kernel<32, 64, 3, 8, 8, 8, 8, 8>
            <<<g3, 256, 0, stream>>>((const unsigned int*)s4, w3, U, 0);
        spike_kernel<<<32768 / 64, 64, 0, stream>>>(U, s5, 32768, 32768, 0, rk);
    }
    // ---- dense + final spike ----
    dim3 g6(NCHUNK, 10, 8);
    dense_u_kernel<<<g6, 64, 0, stream>>>(s5, wfc, U6);
    spike6_kernel<<<1, 128, 0, stream>>>(U6, out, rk);
}

// Round 8
// 361.952 us; speedup vs baseline: 1.7747x; 1.7747x over previous
//
#include <hip/hip_runtime.h>
#include <cmath>

#define T_SAMPLE 300
#define NCHUNK 75   // T / 4

struct RefK { float v[10]; };

// One step of the SLAYER spike recurrence. buf[0..9] = pending refractory.
__device__ __forceinline__ unsigned char spike_step(float u, float* buf, const RefK& rk) {
    const float um = u + buf[0];
    const bool fire = um >= 10.0f;
    const float ev = fire ? 1.0f : 0.0f;
#pragma unroll
    for (int r = 0; r < 9; ++r) buf[r] = fmaf(ev, rk.v[r], buf[r + 1]);
    buf[9] = ev * rk.v[9];
    return fire ? (unsigned char)1 : (unsigned char)0;
}

// ---------------------------------------------------------------------------
// transpose input [B,2,34,34,T] f32 ({0,1}) -> X[tchunk][n][4] u8, n = b,c,y,x
// ---------------------------------------------------------------------------
__global__ __launch_bounds__(256) void transpose_in_kernel(
    const float* __restrict__ In, unsigned int* __restrict__ X)
{
    __shared__ unsigned int lds[16 * NCHUNK];
    const int blk = blockIdx.x;          // 1156 blocks x 16 neurons
    const int tn = threadIdx.x >> 4;     // 0..15 neuron
    const int tq = threadIdx.x & 15;     // 0..15 t-group
    const size_t n = (size_t)blk * 16 + tn;
#pragma unroll
    for (int p = 0; p < 5; ++p) {
        const int ch = p * 16 + tq;
        if (ch < NCHUNK) {
            const float4 v = *(const float4*)(In + n * T_SAMPLE + ch * 4);
            unsigned int u = (v.x != 0.f ? 1u : 0u) | (v.y != 0.f ? 0x100u : 0u) |
                             (v.z != 0.f ? 0x10000u : 0u) | (v.w != 0.f ? 0x1000000u : 0u);
            lds[tn * NCHUNK + ch] = u;
        }
    }
    __syncthreads();
    for (int idx = threadIdx.x; idx < 16 * NCHUNK; idx += 256) {
        const int ch = idx >> 4, t2 = idx & 15;
        X[(size_t)ch * 18496 + blk * 16 + t2] = lds[t2 * NCHUNK + ch];
    }
}

// ---------------------------------------------------------------------------
// conv_u (R3 form, proven best): per-timestep 2D conv (pad=1), 4 timesteps
// per thread. Input: uchar4 t-chunked spikes -> float4 LDS tile. Output:
// float4 t-chunked u. Grid: x = tchunk, y = tile*OG+og, z = local batch
// (nbl runtime). Wave = OPT output channels over an 8x8 tile; lane = pixel.
// ---------------------------------------------------------------------------
template <int IC, int OC, int K, int OH, int OW, int IH, int IW, int OPT>
__global__ __launch_bounds__(256) void conv_u_kernel(
    const uchar4* __restrict__ in_, const float* __restrict__ W,
    float4* __restrict__ U, int b0, int nbl)
{
    constexpr int TH = 8, TW = 8;
    constexpr int EH = TH + K - 1, EW = TW + K - 1;
    constexpr int NTX = OW / TW, NTY = OH / TH, NT = NTX * NTY;
    constexpr int KK = K * K;
    constexpr int E = IC * EH * EW;
    constexpr int PLANE_IN = 8 * IC * IH * IW;   // full-batch chunk plane (uchar4)
    const int PLANE_U = nbl * OC * OH * OW;      // slice chunk plane (float4)

    __shared__ float4 tile[E];

    const int tc = blockIdx.x;
    const int by = blockIdx.y;
    const int til = by % NT;
    const int og = by / NT;
    const int ty = til / NTX, tx = til % NTX;
    const int bl = blockIdx.z;
    const int b = b0 + bl;
    const int tid = threadIdx.x;
    const int wave = tid >> 6, lane = tid & 63;
    const int py = lane >> 3, px = lane & 7;

    // ---- stage: one coalesced uchar4 per element ----
    const int iy0 = ty * TH - 1, ix0 = tx * TW - 1;  // PAD = 1
    const uchar4* ib = in_ + (size_t)tc * PLANE_IN + (size_t)b * IC * IH * IW;
    for (int e = tid; e < E; e += 256) {
        const int c = e / (EH * EW);
        const int r = e % (EH * EW);
        const int iy = r / EW, ix = r % EW;
        const int gy = iy0 + iy, gx = ix0 + ix;
        float4 v = make_float4(0.f, 0.f, 0.f, 0.f);
        if ((unsigned)gy < (unsigned)IH && (unsigned)gx < (unsigned)IW) {
            const uchar4 s = ib[(c * IH + gy) * IW + gx];
            v = make_float4((float)s.x, (float)s.y, (float)s.z, (float)s.w);
        }
        tile[e] = v;
    }
    __syncthreads();

    // ---- compute ----
    float acc[OPT][4];
#pragma unroll
    for (int j = 0; j < OPT; ++j)
#pragma unroll
        for (int k = 0; k < 4; ++k) acc[j][k] = 0.f;

    int ob = (og * 4 + wave) * OPT;
    ob = __builtin_amdgcn_readfirstlane(ob);   // wave-uniform -> scalar weight loads
    const float* Wp = W + (size_t)ob * IC * KK;

    for (int c = 0; c < IC; ++c) {
#pragma unroll
        for (int dy = 0; dy < K; ++dy) {
            float wr[OPT][K];
#pragma unroll
            for (int j = 0; j < OPT; ++j)
#pragma unroll
                for (int dx = 0; dx < K; ++dx)
                    wr[j][dx] = Wp[(j * IC + c) * KK + dy * K + dx];
#pragma unroll
            for (int dx = 0; dx < K; ++dx) {
                const float4 v = tile[((c * EH) + py + dy) * EW + (px + dx)];
#pragma unroll
                for (int j = 0; j < OPT; ++j) {
                    const float w = wr[j][dx];
                    acc[j][0] = fmaf(w, v.x, acc[j][0]);
                    acc[j][1] = fmaf(w, v.y, acc[j][1]);
                    acc[j][2] = fmaf(w, v.z, acc[j][2]);
                    acc[j][3] = fmaf(w, v.w, acc[j][3]);
                }
            }
        }
    }

    const int y = ty * TH + py, x = tx * TW + px;
#pragma unroll
    for (int j = 0; j < OPT; ++j) {
        const int nb = ((bl * OC + (ob + j)) * OH + y) * OW + x;
        U[(size_t)tc * PLANE_U + nb] = make_float4(acc[j][0], acc[j][1], acc[j][2], acc[j][3]);
    }
}

// ---------------------------------------------------------------------------
// spike: per-neuron scan. float4 per chunk in, uchar4 per chunk out. Ring-8.
// 64-thread blocks (grid = nneur/64) for max CU spread.
// ---------------------------------------------------------------------------
__global__ __launch_bounds__(64) void spike_kernel(
    const float4* __restrict__ U, uchar4* __restrict__ S,
    int nneur, int sstride, int soff, RefK rk)
{
    const int n = blockIdx.x * 64 + threadIdx.x;
    const float4* up = U + n;
    uchar4* sp = S + soff + n;
    float buf[10];
#pragma unroll
    for (int r = 0; r < 10; ++r) buf[r] = 0.f;

    float4 ring[8];
#pragma unroll
    for (int r = 0; r < 8; ++r) ring[r] = up[(size_t)r * nneur];

#pragma unroll 8
    for (int ch = 0; ch < 72; ++ch) {
        const float4 cur = ring[ch & 7];
        const int pf = (ch + 8 < NCHUNK) ? ch + 8 : NCHUNK - 1;
        ring[ch & 7] = up[(size_t)pf * nneur];
        uchar4 o;
        o.x = spike_step(cur.x, buf, rk);
        o.y = spike_step(cur.y, buf, rk);
        o.z = spike_step(cur.z, buf, rk);
        o.w = spike_step(cur.w, buf, rk);
        sp[(size_t)ch * sstride] = o;
    }
#pragma unroll
    for (int ch = 72; ch < NCHUNK; ++ch) {
        const float4 cur = ring[ch & 7];
        uchar4 o;
        o.x = spike_step(cur.x, buf, rk);
        o.y = spike_step(cur.y, buf, rk);
        o.z = spike_step(cur.z, buf, rk);
        o.w = spike_step(cur.w, buf, rk);
        sp[(size_t)ch * sstride] = o;
    }
}

// ---------------------------------------------------------------------------
// pool(2)*11 + spike. Two 8-byte loads per chunk (x-pair rows). Ring-8.
// 64-thread blocks.
// ---------------------------------------------------------------------------
__device__ __forceinline__ int bsum4(uint2 r0, uint2 r1, int k) {
    return (int)((r0.x >> (8 * k)) & 0xffu) + (int)((r0.y >> (8 * k)) & 0xffu)
         + (int)((r1.x >> (8 * k)) & 0xffu) + (int)((r1.y >> (8 * k)) & 0xffu);
}

template <int C, int H, int W>
__global__ __launch_bounds__(64) void pool_spike_kernel(
    const uchar4* __restrict__ Sin, uchar4* __restrict__ Sout, RefK rk)
{
    constexpr int H2 = H / 2, W2 = W / 2;
    constexpr int SIN = 8 * C * H * W;     // chunk stride (uchar4 units)
    constexpr int SOUT = 8 * C * H2 * W2;
    const int n = blockIdx.x * 64 + threadIdx.x;   // exact multiple of 64
    const int x = n % W2;
    const int y = (n / W2) % H2;
    const int c = (n / (W2 * H2)) % C;
    const int b = n / (W2 * H2 * C);
    const int base = (((b * C + c) * H + 2 * y) * W + 2 * x);
    uchar4* q = Sout + n;

    float buf[10];
#pragma unroll
    for (int r = 0; r < 10; ++r) buf[r] = 0.f;

    uint2 r0[8], r1[8];
#pragma unroll
    for (int r = 0; r < 8; ++r) {
        r0[r] = *(const uint2*)(Sin + (size_t)r * SIN + base);
        r1[r] = *(const uint2*)(Sin + (size_t)r * SIN + base + W);
    }

#pragma unroll 8
    for (int ch = 0; ch < 72; ++ch) {
        const uint2 a0 = r0[ch & 7], a1 = r1[ch & 7];
        const int pf = (ch + 8 < NCHUNK) ? ch + 8 : NCHUNK - 1;
        r0[ch & 7] = *(const uint2*)(Sin + (size_t)pf * SIN + base);
        r1[ch & 7] = *(const uint2*)(Sin + (size_t)pf * SIN + base + W);
        uchar4 o;
        o.x = spike_step(11.0f * (float)bsum4(a0, a1, 0), buf, rk);
        o.y = spike_step(11.0f * (float)bsum4(a0, a1, 1), buf, rk);
        o.z = spike_step(11.0f * (float)bsum4(a0, a1, 2), buf, rk);
        o.w = spike_step(11.0f * (float)bsum4(a0, a1, 3), buf, rk);
        q[(size_t)ch * SOUT] = o;
    }
#pragma unroll
    for (int ch = 72; ch < NCHUNK; ++ch) {
        const uint2 a0 = r0[ch & 7], a1 = r1[ch & 7];
        uchar4 o;
        o.x = spike_step(11.0f * (float)bsum4(a0, a1, 0), buf, rk);
        o.y = spike_step(11.0f * (float)bsum4(a0, a1, 1), buf, rk);
        o.z = spike_step(11.0f * (float)bsum4(a0, a1, 2), buf, rk);
        o.w = spike_step(11.0f * (float)bsum4(a0, a1, 3), buf, rk);
        q[(size_t)ch * SOUT] = o;
    }
}

// ---------------------------------------------------------------------------
// dense u: U6[tc][b*10+o][4] = sum_site wfc[o,site] * s5[tc][b*4096+site][4]
// ---------------------------------------------------------------------------
__global__ __launch_bounds__(64) void dense_u_kernel(
    const uchar4* __restrict__ S5, const float* __restrict__ WFC,
    float4* __restrict__ U6)
{
    const int tc = blockIdx.x, o = blockIdx.y, b = blockIdx.z;
    const int lane = threadIdx.x;
    float a0 = 0.f, a1 = 0.f, a2 = 0.f, a3 = 0.f;
    const uchar4* sb = S5 + (size_t)tc * 32768 + b * 4096;
    const float* wb = WFC + o * 4096;
    for (int i = 0; i < 64; ++i) {
        const int site = i * 64 + lane;
        const uchar4 s = sb[site];
        const float w = wb[site];
        a0 = fmaf(w, (float)s.x, a0);
        a1 = fmaf(w, (float)s.y, a1);
        a2 = fmaf(w, (float)s.z, a2);
        a3 = fmaf(w, (float)s.w, a3);
    }
#pragma unroll
    for (int m = 1; m < 64; m <<= 1) {
        a0 += __shfl_xor(a0, m, 64);
        a1 += __shfl_xor(a1, m, 64);
        a2 += __shfl_xor(a2, m, 64);
        a3 += __shfl_xor(a3, m, 64);
    }
    if (lane == 0)
        U6[(size_t)tc * 80 + b * 10 + o] = make_float4(a0, a1, a2, a3);
}

// final spike over 80 neurons; float4 chunks in, [n][t] fp32 out.
__global__ __launch_bounds__(128) void spike6_kernel(
    const float4* __restrict__ U6, float* __restrict__ Out, RefK rk)
{
    const int n = threadIdx.x;
    if (n >= 80) return;
    const float4* up = U6 + n;
    float* op = Out + (size_t)n * T_SAMPLE;
    float buf[10];
#pragma unroll
    for (int r = 0; r < 10; ++r) buf[r] = 0.f;

    float4 ring[8];
#pragma unroll
    for (int r = 0; r < 8; ++r) ring[r] = up[(size_t)r * 80];

#pragma unroll 8
    for (int ch = 0; ch < 72; ++ch) {
        const float4 cur = ring[ch & 7];
        const int pf = (ch + 8 < NCHUNK) ? ch + 8 : NCHUNK - 1;
        ring[ch & 7] = up[(size_t)pf * 80];
        float4 o;
        o.x = (float)spike_step(cur.x, buf, rk);
        o.y = (float)spike_step(cur.y, buf, rk);
        o.z = (float)spike_step(cur.z, buf, rk);
        o.w = (float)spike_step(cur.w, buf, rk);
        *(float4*)(op + ch * 4) = o;
    }
#pragma unroll
    for (int ch = 72; ch < NCHUNK; ++ch) {
        const float4 cur = ring[ch & 7];
        float4 o;
        o.x = (float)spike_step(cur.x, buf, rk);
        o.y = (float)spike_step(cur.y, buf, rk);
        o.z = (float)spike_step(cur.z, buf, rk);
        o.w = (float)spike_step(cur.w, buf, rk);
        *(float4*)(op + ch * 4) = o;
    }
}

extern "C" void kernel_launch(void* const* d_in, const int* in_sizes, int n_in,
                              void* d_out, int out_size, void* d_ws, size_t ws_size,
                              hipStream_t stream)
{
    const float* spikeIn = (const float*)d_in[0];  // [8,2,34,34,300]
    const float* w1 = (const float*)d_in[1];       // [16,2,5,5]
    const float* w2 = (const float*)d_in[2];       // [32,16,3,3]
    const float* w3 = (const float*)d_in[3];       // [64,32,3,3]
    const float* wfc = (const float*)d_in[4];      // [10,64,8,8]
    float* out = (float*)d_out;                    // [8,10,1,1,300]

    RefK rk;
    for (int t = 1; t <= 10; ++t)
        rk.v[t - 1] = (float)(-20.0 * (double)t * std::exp(1.0 - (double)t));

    // workspace, all t-chunked [tc][neuron][4]:
    //   U : 39.32 MB (small path) or 78.64 MB (big path) float4 u-chunks
    //   A : 39.32 MB uchar4 s1 -> s3 -> s5
    //   B :  9.83 MB uchar4 X (5.55 MB) then s2 -> s4
    //   U6:  0.096 MB float4[75*80]
    // Big path (ws_size permitting) halves conv1/conv2 launch counts.
    const size_t A_BYTES = 39321600;
    const size_t B_BYTES = 9830400;
    const size_t U6_BYTES = 96000;
    const size_t U_BIG = 78643200, U_SMALL = 39321600;
    const bool big = ws_size >= U_BIG + A_BYTES + B_BYTES + U6_BYTES;
    const size_t U_BYTES = big ? U_BIG : U_SMALL;

    char* ws = (char*)d_ws;
    float4* U = (float4*)ws;
    uchar4* A = (uchar4*)(ws + U_BYTES);
    uchar4* Bb = (uchar4*)(ws + U_BYTES + A_BYTES);
    float4* U6 = (float4*)(ws + U_BYTES + A_BYTES + B_BYTES);

    uchar4* X = Bb;   // input transpose; dead after layer 1
    uchar4* s1 = A;
    uchar4* s2 = Bb;
    uchar4* s3 = A;   // s1 dead after pool2
    uchar4* s4 = Bb;  // s2 dead after conv2-u
    uchar4* s5 = A;   // s3 dead after pool4

    // ---- input transpose ----
    transpose_in_kernel<<<18496 / 16, 256, 0, stream>>>(spikeIn, (unsigned int*)X);

    // ---- layer 1: conv(2->16, k5) + spike ----
    const int nbl1 = big ? 4 : 2;
    for (int b0 = 0; b0 < 8; b0 += nbl1) {
        dim3 g1(NCHUNK, 16, nbl1);  // 16 tiles, OG=1
        conv_u_kernel<2, 16, 5, 32, 32, 34, 34, 4>
            <<<g1, 256, 0, stream>>>(X, w1, U, b0, nbl1);
        const int nn = nbl1 * 16384;
        spike_kernel<<<nn / 64, 64, 0, stream>>>(
            U, s1, nn, 131072, b0 * 16384, rk);
    }
    // ---- pool2 + spike ----
    pool_spike_kernel<16, 32, 32><<<32768 / 64, 64, 0, stream>>>(s1, s2, rk);
    // ---- layer 2: conv(16->32, k3) + spike ----
    const int nbl2 = big ? 8 : 4;
    for (int b0 = 0; b0 < 8; b0 += nbl2) {
        dim3 g2(NCHUNK, 4, nbl2);   // 4 tiles, OG=1
        conv_u_kernel<16, 32, 3, 16, 16, 16, 16, 8>
            <<<g2, 256, 0, stream>>>(s2, w2, U, b0, nbl2);
        const int nn = nbl2 * 8192;
        spike_kernel<<<nn / 64, 64, 0, stream>>>(
            U, s3, nn, 65536, b0 * 8192, rk);
    }
    // ---- pool4 + spike ----
    pool_spike_kernel<32, 16, 16><<<16384 / 64, 64, 0, stream>>>(s3, s4, rk);
    // ---- layer 3: conv(32->64, k3) + spike, full batch ----
    {
        dim3 g3(NCHUNK, 2, 8);   // 1 tile, OG=2
        conv_u_kernel<32, 64, 3, 8, 8, 8, 8, 8>
            <<<g3, 256, 0, stream>>>(s4, w3, U, 0, 8);
        spike_kernel<<<32768 / 64, 64, 0, stream>>>(U, s5, 32768, 32768, 0, rk);
    }
    // ---- dense + final spike ----
    dim3 g6(NCHUNK, 10, 8);
    dense_u_kernel<<<g6, 64, 0, stream>>>(s5, wfc, U6);
    spike6_kernel<<<1, 128, 0, stream>>>(U6, out, rk);
}